// Round 4
// baseline (358.081 us; speedup 1.0000x reference)
//
#include <hip/hip_runtime.h>
#include <cstdint>
#include <cstddef>

// LIF recurrent SNN, sinabs ThresholdSubtract.
//   B=32 independent batch rows -> 1 block per batch, state in registers.
//   Spikes ~4.4 sigma -> speculate "no spike in chunk", exact replay on hit.
// Round-3/4:
//   * Staging via global_load_lds DMA into THREE separate __shared__ buffers
//     (separate objects => LLVM per-object LDS-DMA waitcnt stays precise,
//     no conservative vmcnt(0) drain before ds_read). R2's VGPR buffers were
//     demoted by the register allocator (VGPR_Count=72 < 96 needed) which
//     forced a latency-exposed copy per chunk.
//   * Output zeroing fused into the same launch (blocks >=32 zero `out` with
//     non-temporal stores on the other 224 CUs, concurrent with lif). Replay
//     emits compact spike records to d_ws; a tiny scatter kernel applies them
//     afterwards. Removes ~35us+ of zeroing from the critical path.
//   * R4 fix: __builtin_nontemporal_store requires an ext_vector_type pointer,
//     not HIP's float4 class -> use v4f in the zero path.
#define B_       32
#define T_       1000
#define N_       1024
#define THREADS_ 256           // 4 waves; each thread owns 4 consecutive neurons
#define WAVES_   4
#define CHUNK_   8
#define NCHUNK_  (T_ / CHUNK_) // 125 = 3*41 + 2
#define ZBLOCKS_ 2048

typedef float v4f __attribute__((ext_vector_type(4)));

// Barrier draining only LDS (lgkmcnt), NOT vmcnt: prefetch DMAs for future
// chunks stay in flight across the per-chunk spike-exchange barrier.
__device__ __forceinline__ void barrier_lds() {
  __asm__ volatile("s_waitcnt lgkmcnt(0)\n\ts_barrier" ::: "memory");
}

// Wait until at most N vmem ops outstanding. vmcnt is FIFO: with chunks of 8
// DMA loads issued in order, waiting to 16 guarantees the 3rd-newest chunk's
// loads have landed in LDS; any interleaved (rare) replay loads/stores are
// newer and only cause harmless over-drain.
#define VMWAIT(N) __asm__ volatile("s_waitcnt vmcnt(" #N ")" ::: "memory")

typedef const __attribute__((address_space(1))) void* gas_ptr;
typedef __attribute__((address_space(3))) void*       las_ptr;

__global__ __launch_bounds__(THREADS_, 1)
void lif_fused(const float* __restrict__ x, const float* __restrict__ w,
               const float* __restrict__ brec_g, float* __restrict__ out,
               unsigned long long* __restrict__ ws_rec,
               unsigned int* __restrict__ ws_cnt, int cap)
{
  // ---------------- zero path: blocks >= 32 clear the output ----------------
  if (blockIdx.x >= B_) {
    const size_t n4 = (size_t)B_ * T_ * N_ / 4;
    size_t i = (size_t)(blockIdx.x - B_) * THREADS_ + threadIdx.x;
    const size_t stride = (size_t)(gridDim.x - B_) * THREADS_;
    v4f* o4 = (v4f*)out;
    v4f z = (v4f)(0.f);
    for (; i < n4; i += stride) __builtin_nontemporal_store(z, &o4[i]);
    return;
  }

  // ---------------- lif path: blocks 0..31, one batch row each --------------
  const int b    = blockIdx.x;
  const int tid  = threadIdx.x;
  const int lane = tid & 63;
  const int wv   = tid >> 6;
  const int n0   = tid << 2;

  // THREE separate LDS chunk buffers (96KB) -- separate objects on purpose.
  __shared__ float xbuf0[CHUNK_][N_];
  __shared__ float xbuf1[CHUNK_][N_];
  __shared__ float xbuf2[CHUNK_][N_];
  // Parity-double-buffered exchange: one barrier per chunk/step, no resets.
  __shared__ unsigned long long s_cmask[2][WAVES_];
  __shared__ unsigned long long s_mask [2][WAVES_];
  __shared__ v4f                s_val  [2][THREADS_];
  __shared__ unsigned int       s_spkcnt;

  if (tid == 0) s_spkcnt = 0;   // visible by the first chunk's barrier_lds

  // per-lane global source: this wave's 256-neuron slice of batch row b
  const float* xg = x + (size_t)b * T_ * N_ + (wv << 8) + (lane << 2);

  v4f state = (v4f)(0.f);
  v4f rec   = (v4f)(0.f);                 // initial carry rec = 0 (NOT b_rec)
  const v4f brec = *(const v4f*)(brec_g + n0);

  // DMA one 8-step chunk into an LDS buffer; each wave loads exactly the slice
  // it will read (lds dest = wave-uniform base + lane*16 -> floats
  // [wv*256 + lane*4 .. +3] of each step row). No cross-wave vmcnt dependency.
#define ISSUE_LDS(bufv, c)                                                   \
  do {                                                                       \
    const float* _g = xg + (size_t)(c) * (CHUNK_ * N_);                      \
    _Pragma("unroll")                                                        \
    for (int _k = 0; _k < CHUNK_; ++_k)                                      \
      __builtin_amdgcn_global_load_lds((gas_ptr)(_g + (size_t)_k * N_),      \
                                       (las_ptr)&bufv[_k][wv << 8],          \
                                       16, 0, 0);                            \
  } while (0)

  // process one chunk whose data sits in LDS rows xrow[k*N_ + n0 .. +3]
  auto process = [&](const float* xrow, int c) {
    v4f xs[CHUNK_];
#pragma unroll
    for (int k = 0; k < CHUNK_; ++k)
      xs[k] = *(const v4f*)(xrow + (size_t)k * N_ + n0);

    // ---- speculative pass: assume zero spikes block-wide this chunk ----
    // Spike at step k iff pre-update state >= 1.0; track running max.
    // (st-0)*0.9+0.1*t == st*0.9+0.1*t: bit-identical to replay with act==0.
    v4f st = state;
    v4f r  = rec;               // incoming rec (brec unless prev chunk spiked)
    v4f cmax = st;
#pragma unroll
    for (int k = 0; k < CHUNK_; ++k) {
      cmax.x = fmaxf(cmax.x, st.x);
      cmax.y = fmaxf(cmax.y, st.y);
      cmax.z = fmaxf(cmax.z, st.z);
      cmax.w = fmaxf(cmax.w, st.w);
      v4f t = xs[k] + r;
      st = st * 0.9f + 0.1f * t;
      r = brec;                 // no-spike assumption: rec_{t+1} = b_rec
    }
    float m = fmaxf(fmaxf(cmax.x, cmax.y), fmaxf(cmax.z, cmax.w));
    int any = (m >= 1.0f);

    const int p = c & 1;
    unsigned long long wm = __ballot(any);
    if (lane == 0) s_cmask[p][wv] = wm;
    barrier_lds();
    unsigned long long anyblk =
        s_cmask[p][0] | s_cmask[p][1] | s_cmask[p][2] | s_cmask[p][3];

    if (anyblk == 0ULL) {
      state = st;               // fast path: commit; output rows stay zero
      rec   = brec;
      return;
    }

    // ---- exact replay of the chunk with per-step spike exchange ----
    st = state;
    r  = rec;
#pragma unroll 1
    for (int k = 0; k < CHUNK_; ++k) {
      const int q = k & 1;
      float tx = xs[k].x + r.x, ty = xs[k].y + r.y,
            tz = xs[k].z + r.z, tw = xs[k].w + r.w;
      float ax = (st.x > 0.f) ? floorf(st.x) : 0.f;
      float ay = (st.y > 0.f) ? floorf(st.y) : 0.f;
      float az = (st.z > 0.f) ? floorf(st.z) : 0.f;
      float aw = (st.w > 0.f) ? floorf(st.w) : 0.f;
      int ms = (ax != 0.f) | (ay != 0.f) | (az != 0.f) | (aw != 0.f);
      if (ms) {
        v4f v; v.x = ax; v.y = ay; v.z = az; v.w = aw;
        s_val[q][tid] = v;
        // append compact spike records (offset within batch row, value)
        unsigned int off = (unsigned int)((c * CHUNK_ + k) * N_ + n0);
        float av[4] = {ax, ay, az, aw};
#pragma unroll
        for (int e = 0; e < 4; ++e) {
          if (av[e] != 0.f) {
            unsigned int idx = atomicAdd(&s_spkcnt, 1u);
            if ((int)idx < cap)
              ws_rec[(size_t)b * cap + idx] =
                  ((unsigned long long)(off + e) << 32) |
                  (unsigned long long)__float_as_uint(av[e]);
          }
        }
      }
      unsigned long long sm = __ballot(ms);
      if (lane == 0) s_mask[q][wv] = sm;
      st.x = (st.x - ax) * 0.9f + 0.1f * tx;
      st.y = (st.y - ay) * 0.9f + 0.1f * ty;
      st.z = (st.z - az) * 0.9f + 0.1f * tz;
      st.w = (st.w - aw) * 0.9f + 0.1f * tw;
      barrier_lds();
      // sparse rank-1 rec update: rec[n] = b_rec[n] + sum_j act[j]*w[n][j]
      v4f racc = brec;
#pragma unroll 1
      for (int w2 = 0; w2 < WAVES_; ++w2) {
        unsigned long long mm = s_mask[q][w2];
        while (mm) {
          int l = __builtin_ctzll(mm);
          mm &= mm - 1;
          int j = (w2 << 6) + l;
          v4f v = s_val[q][j];
          int jn = j << 2;
          if (v.x != 0.f) {
            racc.x += v.x * w[(size_t)(n0 + 0) * N_ + jn];
            racc.y += v.x * w[(size_t)(n0 + 1) * N_ + jn];
            racc.z += v.x * w[(size_t)(n0 + 2) * N_ + jn];
            racc.w += v.x * w[(size_t)(n0 + 3) * N_ + jn];
          }
          if (v.y != 0.f) {
            int j1 = jn + 1;
            racc.x += v.y * w[(size_t)(n0 + 0) * N_ + j1];
            racc.y += v.y * w[(size_t)(n0 + 1) * N_ + j1];
            racc.z += v.y * w[(size_t)(n0 + 2) * N_ + j1];
            racc.w += v.y * w[(size_t)(n0 + 3) * N_ + j1];
          }
          if (v.z != 0.f) {
            int j2 = jn + 2;
            racc.x += v.z * w[(size_t)(n0 + 0) * N_ + j2];
            racc.y += v.z * w[(size_t)(n0 + 1) * N_ + j2];
            racc.z += v.z * w[(size_t)(n0 + 2) * N_ + j2];
            racc.w += v.z * w[(size_t)(n0 + 3) * N_ + j2];
          }
          if (v.w != 0.f) {
            int j3 = jn + 3;
            racc.x += v.w * w[(size_t)(n0 + 0) * N_ + j3];
            racc.y += v.w * w[(size_t)(n0 + 1) * N_ + j3];
            racc.z += v.w * w[(size_t)(n0 + 2) * N_ + j3];
            racc.w += v.w * w[(size_t)(n0 + 3) * N_ + j3];
          }
        }
      }
      r = racc;
    }
    state = st;
    rec   = r;
  };

  // ---- depth-2 modulo-scheduled chunk pipeline over 3 LDS buffers ----
  // Steady state: {c, c+1, c+2} in flight (24 DMAs); VMWAIT(16) drains the
  // oldest chunk exactly. Tail chunks 123/124 need deeper drains.
  const float* x0row = &xbuf0[0][0];
  const float* x1row = &xbuf1[0][0];
  const float* x2row = &xbuf2[0][0];

  ISSUE_LDS(xbuf0, 0);
  ISSUE_LDS(xbuf1, 1);

  int c = 0;
#pragma unroll 1
  for (int t3 = 0; t3 < 41; ++t3) {   // processes chunks 0..122
    ISSUE_LDS(xbuf2, c + 2);
    VMWAIT(16);
    process(x0row, c);
    ISSUE_LDS(xbuf0, c + 3);
    VMWAIT(16);
    process(x1row, c + 1);
    ISSUE_LDS(xbuf1, c + 4);
    VMWAIT(16);
    process(x2row, c + 2);
    c += 3;
  }
  // tail: chunks 123 (xbuf0) and 124 (xbuf1) already issued
  VMWAIT(8);
  process(x0row, 123);
  VMWAIT(0);
  process(x1row, 124);

  __syncthreads();                     // all replay appends done
  if (tid == 0) ws_cnt[b] = s_spkcnt;  // written unconditionally (ws poisoned)
#undef ISSUE_LDS
}

// Apply the (few hundred) recorded spikes onto the zeroed output.
__global__ void scatter_spikes(const unsigned long long* __restrict__ rec,
                               const unsigned int* __restrict__ cnt,
                               float* __restrict__ out, int cap)
{
  int b = blockIdx.x;
  unsigned int n = cnt[b];
  if ((int)n > cap) n = cap;
  for (unsigned int i = threadIdx.x; i < n; i += blockDim.x) {
    unsigned long long r = rec[(size_t)b * cap + i];
    unsigned int off = (unsigned int)(r >> 32);
    float v = __uint_as_float((unsigned int)r);
    out[(size_t)b * (T_ * N_) + off] = v;
  }
}

extern "C" void kernel_launch(void* const* d_in, const int* in_sizes, int n_in,
                              void* d_out, int out_size, void* d_ws, size_t ws_size,
                              hipStream_t stream) {
  const float* x  = (const float*)d_in[0]; // [B,T,N] input_current
  const float* w  = (const float*)d_in[1]; // [N,N] w_rec (row-major [out,in])
  const float* br = (const float*)d_in[2]; // [N] b_rec
  float* out = (float*)d_out;              // [B,T,N] spikes

  // spike-record workspace layout: [32][cap] u64 records, then [32] u32 counts
  int cap = 4096;
  size_t need = (size_t)B_ * cap * 8 + B_ * 4;
  if (ws_size < need && ws_size > 256)
    cap = (int)((ws_size - 256) / ((size_t)B_ * 8));
  unsigned long long* rec = (unsigned long long*)d_ws;
  unsigned int* cnt = (unsigned int*)((char*)d_ws + (size_t)B_ * cap * 8);

  // blocks 0..31: sequential LIF scan (1 block/batch row);
  // blocks 32..: zero the output concurrently on the remaining CUs.
  lif_fused<<<B_ + ZBLOCKS_, THREADS_, 0, stream>>>(x, w, br, out, rec, cnt, cap);
  scatter_spikes<<<B_, THREADS_, 0, stream>>>(rec, cnt, out, cap);
}

// Round 5
// 353.814 us; speedup vs baseline: 1.0121x; 1.0121x over previous
//
#include <hip/hip_runtime.h>
#include <cstdint>
#include <cstddef>

// LIF recurrent SNN, sinabs ThresholdSubtract.
//   B=32 independent batch rows -> 1 block per batch, state in registers.
//   Spikes ~4.4 sigma -> speculate "no spike in chunk", exact replay on hit.
// Round-5:
//   * VGPR prefetch buffers as NAMED-FIELD structs (no arrays, no references,
//     no dynamic indexing anywhere) -> SROA keeps them in registers. R1/R2
//     failed because xs[k] runtime indexing / by-ref lambda params took the
//     buffer's address -> scratch demotion (VGPR_Count 32/72 proved it).
//   * R4's global_load_lds triple-buffer failed differently: the waitcnt pass
//     tracks LDS-DMA by memory (not dest reg) and can't disambiguate buffers,
//     so it emitted vmcnt(0) before every ds_read -> prefetch distance 0.
//   * Loads issued via inline-asm global_load_dwordx4; consumption gated by
//     s_waitcnt vmcnt(16) asm with "+v" ties (waitcnt pass can't see through
//     INLINEASM, so the manual wait is REQUIRED for correctness).
//   * Replay re-reads x from GLOBAL memory (rare path) -> no register-array
//     indexing; exchange/commit logic identical to the R4-validated code.
//   * Output zeroing stays fused (blocks >= 32, nontemporal stores); spikes
//     go to d_ws records, applied by a tiny scatter kernel.
#define B_       32
#define T_       1000
#define N_       1024
#define THREADS_ 256           // 4 waves; each thread owns 4 consecutive neurons
#define WAVES_   4
#define CHUNK_   8
#define ZBLOCKS_ 2048

typedef float v4f __attribute__((ext_vector_type(4)));

// Barrier draining only LDS (lgkmcnt), NOT vmcnt: prefetched global loads for
// future chunks stay in flight across the per-chunk exchange barrier.
__device__ __forceinline__ void barrier_lds() {
  __asm__ volatile("s_waitcnt lgkmcnt(0)\n\ts_barrier" ::: "memory");
}

__device__ __forceinline__ v4f vmax4(v4f a, v4f b) {
  v4f r;
  r.x = fmaxf(a.x, b.x); r.y = fmaxf(a.y, b.y);
  r.z = fmaxf(a.z, b.z); r.w = fmaxf(a.w, b.w);
  return r;
}

// One 8-step chunk of this thread's 4 neurons, in 32 architected VGPRs.
struct Chunk { v4f x0, x1, x2, x3, x4, x5, x6, x7; };

#define ISSUE1(dst, p)                                                       \
  __asm__ volatile("global_load_dwordx4 %0, %1, off"                         \
                   : "=&v"(dst) : "v"(p) : "memory")

// Issue 8 loads for chunk cc into buf (asm volatile pins the issue point).
#define ISSUE(buf, cc)                                                       \
  do {                                                                       \
    const float* _g = xg + (size_t)(cc) * (CHUNK_ * N_);                     \
    ISSUE1(buf.x0, (const v4f*)(_g + 0 * N_));                               \
    ISSUE1(buf.x1, (const v4f*)(_g + 1 * N_));                               \
    ISSUE1(buf.x2, (const v4f*)(_g + 2 * N_));                               \
    ISSUE1(buf.x3, (const v4f*)(_g + 3 * N_));                               \
    ISSUE1(buf.x4, (const v4f*)(_g + 4 * N_));                               \
    ISSUE1(buf.x5, (const v4f*)(_g + 5 * N_));                               \
    ISSUE1(buf.x6, (const v4f*)(_g + 6 * N_));                               \
    ISSUE1(buf.x7, (const v4f*)(_g + 7 * N_));                               \
  } while (0)

// Wait until <= IMM vmem ops outstanding, tying buf's registers so no
// consumer can be scheduled above the wait. vmcnt decrements in order; buf's
// 8 loads are the oldest outstanding at each call site, so vmcnt(16) (with
// two newer chunks = 16 ops in flight) guarantees buf is complete. Any
// replay-path loads/stores are newer and only make the wait stronger.
#define WAITQ(buf, IMM)                                                      \
  __asm__ volatile("s_waitcnt vmcnt(" #IMM ")"                               \
                   : "+v"(buf.x0), "+v"(buf.x1), "+v"(buf.x2), "+v"(buf.x3), \
                     "+v"(buf.x4), "+v"(buf.x5), "+v"(buf.x6), "+v"(buf.x7)  \
                   :                                                         \
                   : "memory")

#define SPEC_STEP(xf)                                                        \
  do {                                                                       \
    cmax = vmax4(cmax, st);                                                  \
    v4f _t = (xf) + rr;                                                      \
    st = st * 0.9f + 0.1f * _t;                                              \
    rr = brec;                                                               \
  } while (0)

// Process one chunk: speculative no-spike pass over named fields (constant
// indices only); block-wide ballot; exact replay (rare) via `replay`.
#define PROCESS(buf, cc)                                                     \
  do {                                                                       \
    v4f st = state, rr = rec, cmax = state;                                  \
    SPEC_STEP(buf.x0); SPEC_STEP(buf.x1); SPEC_STEP(buf.x2);                 \
    SPEC_STEP(buf.x3); SPEC_STEP(buf.x4); SPEC_STEP(buf.x5);                 \
    SPEC_STEP(buf.x6); SPEC_STEP(buf.x7);                                    \
    float _m = fmaxf(fmaxf(cmax.x, cmax.y), fmaxf(cmax.z, cmax.w));          \
    int _any = (_m >= 1.0f);                                                 \
    const int _p = (cc) & 1;                                                 \
    unsigned long long _wm = __ballot(_any);                                 \
    if (lane == 0) s_cmask[_p][wv] = _wm;                                    \
    barrier_lds();                                                           \
    unsigned long long _ab =                                                 \
        s_cmask[_p][0] | s_cmask[_p][1] | s_cmask[_p][2] | s_cmask[_p][3];   \
    if (_ab == 0ULL) { state = st; rec = brec; }                             \
    else { replay(cc); }                                                     \
  } while (0)

typedef const __attribute__((address_space(1))) void* gas_ptr;

__global__ __launch_bounds__(THREADS_, 1)
void lif_fused(const float* __restrict__ x, const float* __restrict__ w,
               const float* __restrict__ brec_g, float* __restrict__ out,
               unsigned long long* __restrict__ ws_rec,
               unsigned int* __restrict__ ws_cnt, int cap)
{
  // ---------------- zero path: blocks >= 32 clear the output ----------------
  if (blockIdx.x >= B_) {
    const size_t n4 = (size_t)B_ * T_ * N_ / 4;
    size_t i = (size_t)(blockIdx.x - B_) * THREADS_ + threadIdx.x;
    const size_t stride = (size_t)(gridDim.x - B_) * THREADS_;
    v4f* o4 = (v4f*)out;
    v4f z = (v4f)(0.f);
    for (; i < n4; i += stride) __builtin_nontemporal_store(z, &o4[i]);
    return;
  }

  // ---------------- lif path: blocks 0..31, one batch row each --------------
  const int b    = blockIdx.x;
  const int tid  = threadIdx.x;
  const int lane = tid & 63;
  const int wv   = tid >> 6;
  const int n0   = tid << 2;

  // Parity-double-buffered exchange: one barrier per chunk/step, no resets.
  __shared__ unsigned long long s_cmask[2][WAVES_];
  __shared__ unsigned long long s_mask [2][WAVES_];
  __shared__ v4f                s_val  [2][THREADS_];
  __shared__ unsigned int       s_spkcnt;

  if (tid == 0) s_spkcnt = 0;   // ordered by the first chunk's barrier_lds

  // this thread's 4-neuron column of batch row b
  const float* xg = x + (size_t)b * T_ * N_ + n0;

  v4f state = (v4f)(0.f);
  v4f rec   = (v4f)(0.f);                 // initial carry rec = 0 (NOT b_rec)
  const v4f brec = *(const v4f*)(brec_g + n0);

  // Exact replay of chunk cc (rare): re-reads x from GLOBAL (no register
  // arrays), per-step spike exchange, sparse rank-1 rec update, spike records.
  auto replay = [&](int cc) {
    v4f st = state;
    v4f r  = rec;
    const float* xrep = xg + (size_t)cc * (CHUNK_ * N_);
#pragma unroll 1
    for (int k = 0; k < CHUNK_; ++k) {
      const int q = k & 1;
      v4f xv = *(const v4f*)(xrep + (size_t)k * N_);
      float tx = xv.x + r.x, ty = xv.y + r.y, tz = xv.z + r.z, tw = xv.w + r.w;
      float ax = (st.x > 0.f) ? floorf(st.x) : 0.f;
      float ay = (st.y > 0.f) ? floorf(st.y) : 0.f;
      float az = (st.z > 0.f) ? floorf(st.z) : 0.f;
      float aw = (st.w > 0.f) ? floorf(st.w) : 0.f;
      int ms = (ax != 0.f) | (ay != 0.f) | (az != 0.f) | (aw != 0.f);
      if (ms) {
        v4f v; v.x = ax; v.y = ay; v.z = az; v.w = aw;
        s_val[q][tid] = v;
        unsigned int off = (unsigned int)((cc * CHUNK_ + k) * N_ + n0);
        float av[4] = {ax, ay, az, aw};
#pragma unroll
        for (int e = 0; e < 4; ++e) {
          if (av[e] != 0.f) {
            unsigned int idx = atomicAdd(&s_spkcnt, 1u);
            if ((int)idx < cap)
              ws_rec[(size_t)b * cap + idx] =
                  ((unsigned long long)(off + e) << 32) |
                  (unsigned long long)__float_as_uint(av[e]);
          }
        }
      }
      unsigned long long sm = __ballot(ms);
      if (lane == 0) s_mask[q][wv] = sm;
      st.x = (st.x - ax) * 0.9f + 0.1f * tx;
      st.y = (st.y - ay) * 0.9f + 0.1f * ty;
      st.z = (st.z - az) * 0.9f + 0.1f * tz;
      st.w = (st.w - aw) * 0.9f + 0.1f * tw;
      barrier_lds();
      // sparse rank-1 rec update: rec[n] = b_rec[n] + sum_j act[j]*w[n][j]
      v4f racc = brec;
#pragma unroll 1
      for (int w2 = 0; w2 < WAVES_; ++w2) {
        unsigned long long mm = s_mask[q][w2];
        while (mm) {
          int l = __builtin_ctzll(mm);
          mm &= mm - 1;
          int j = (w2 << 6) + l;
          v4f v = s_val[q][j];
          int jn = j << 2;
          if (v.x != 0.f) {
            racc.x += v.x * w[(size_t)(n0 + 0) * N_ + jn];
            racc.y += v.x * w[(size_t)(n0 + 1) * N_ + jn];
            racc.z += v.x * w[(size_t)(n0 + 2) * N_ + jn];
            racc.w += v.x * w[(size_t)(n0 + 3) * N_ + jn];
          }
          if (v.y != 0.f) {
            int j1 = jn + 1;
            racc.x += v.y * w[(size_t)(n0 + 0) * N_ + j1];
            racc.y += v.y * w[(size_t)(n0 + 1) * N_ + j1];
            racc.z += v.y * w[(size_t)(n0 + 2) * N_ + j1];
            racc.w += v.y * w[(size_t)(n0 + 3) * N_ + j1];
          }
          if (v.z != 0.f) {
            int j2 = jn + 2;
            racc.x += v.z * w[(size_t)(n0 + 0) * N_ + j2];
            racc.y += v.z * w[(size_t)(n0 + 1) * N_ + j2];
            racc.z += v.z * w[(size_t)(n0 + 2) * N_ + j2];
            racc.w += v.z * w[(size_t)(n0 + 3) * N_ + j2];
          }
          if (v.w != 0.f) {
            int j3 = jn + 3;
            racc.x += v.w * w[(size_t)(n0 + 0) * N_ + j3];
            racc.y += v.w * w[(size_t)(n0 + 1) * N_ + j3];
            racc.z += v.w * w[(size_t)(n0 + 2) * N_ + j3];
            racc.w += v.w * w[(size_t)(n0 + 3) * N_ + j3];
          }
        }
      }
      r = racc;
    }
    state = st;
    rec   = r;
  };

  // ---- depth-2 modulo-scheduled chunk pipeline over 3 register buffers ----
  // Steady state: chunks {c, c+1, c+2} in flight = 24 loads; WAITQ(..,16)
  // drains exactly the oldest chunk's 8 loads.
  Chunk bufA, bufB, bufC;
  ISSUE(bufA, 0);
  ISSUE(bufB, 1);

  int c = 0;
#pragma unroll 1
  for (int t3 = 0; t3 < 41; ++t3) {   // processes chunks 0..122
    ISSUE(bufC, c + 2);
    WAITQ(bufA, 16);
    PROCESS(bufA, c);
    ISSUE(bufA, c + 3);
    WAITQ(bufB, 16);
    PROCESS(bufB, c + 1);
    ISSUE(bufB, c + 4);
    WAITQ(bufC, 16);
    PROCESS(bufC, c + 2);
    c += 3;
  }
  // tail: chunks 123 (bufA) and 124 (bufB) already issued
  WAITQ(bufA, 8);
  PROCESS(bufA, 123);
  WAITQ(bufB, 0);
  PROCESS(bufB, 124);

  __syncthreads();                     // all replay appends done
  if (tid == 0) ws_cnt[b] = s_spkcnt;  // written unconditionally (ws poisoned)
}

// Apply the (few hundred) recorded spikes onto the zeroed output.
__global__ void scatter_spikes(const unsigned long long* __restrict__ rec,
                               const unsigned int* __restrict__ cnt,
                               float* __restrict__ out, int cap)
{
  int b = blockIdx.x;
  unsigned int n = cnt[b];
  if ((int)n > cap) n = cap;
  for (unsigned int i = threadIdx.x; i < n; i += blockDim.x) {
    unsigned long long r = rec[(size_t)b * cap + i];
    unsigned int off = (unsigned int)(r >> 32);
    float v = __uint_as_float((unsigned int)r);
    out[(size_t)b * (T_ * N_) + off] = v;
  }
}

extern "C" void kernel_launch(void* const* d_in, const int* in_sizes, int n_in,
                              void* d_out, int out_size, void* d_ws, size_t ws_size,
                              hipStream_t stream) {
  const float* x  = (const float*)d_in[0]; // [B,T,N] input_current
  const float* w  = (const float*)d_in[1]; // [N,N] w_rec (row-major [out,in])
  const float* br = (const float*)d_in[2]; // [N] b_rec
  float* out = (float*)d_out;              // [B,T,N] spikes

  // spike-record workspace layout: [32][cap] u64 records, then [32] u32 counts
  int cap = 4096;
  size_t need = (size_t)B_ * cap * 8 + B_ * 4;
  if (ws_size < need && ws_size > 256)
    cap = (int)((ws_size - 256) / ((size_t)B_ * 8));
  unsigned long long* rec = (unsigned long long*)d_ws;
  unsigned int* cnt = (unsigned int*)((char*)d_ws + (size_t)B_ * cap * 8);

  // blocks 0..31: sequential LIF scan (1 block/batch row);
  // blocks 32..: zero the output concurrently on the remaining CUs.
  lif_fused<<<B_ + ZBLOCKS_, THREADS_, 0, stream>>>(x, w, br, out, rec, cnt, cap);
  scatter_spikes<<<B_, THREADS_, 0, stream>>>(rec, cnt, out, cap);
}

// Round 6
// 344.411 us; speedup vs baseline: 1.0397x; 1.0273x over previous
//
#include <hip/hip_runtime.h>
#include <cstdint>
#include <cstddef>

// LIF recurrent SNN, sinabs ThresholdSubtract.
//   B=32 independent batch rows -> 1 block per batch, state in registers.
//   Spikes ~4.4 sigma -> speculate "no spike in chunk", exact replay on hit.
// Round-6: PLAIN SSA LOADS into named-field struct buffers (no inline asm, no
//   arrays, no dynamic indexing). Ledger of prior pipeline failures:
//     R1: arrays + runtime-index replay -> scratch demotion (VGPR 32).
//     R2/R5: inline-asm global_load: defs opaque to RA + waitcnt pass ->
//            buffers split/demoted (VGPR 72/68), pipeline dead.
//     R4: global_load_lds triple-buffer: waitcnt pass can't disambiguate
//         LDS-DMA by buffer -> vmcnt(0) before every ds_read.
//   Plain loads are the one mechanism the backend handles precisely:
//   per-register vmcnt(N) before first use (guide G7), SSA values stay in
//   VGPRs (512/wave budget at 1 wave/SIMD). Loads for chunk c+2 sit before
//   chunk c's lgkm-only barrier ("memory" clobber pins order), first use is
//   2 chunks later -> prefetch distance 2 survives.
#define B_       32
#define T_       1000
#define N_       1024
#define THREADS_ 256           // 4 waves; each thread owns 4 consecutive neurons
#define WAVES_   4
#define CHUNK_   8
#define ZBLOCKS_ 2048

typedef float v4f __attribute__((ext_vector_type(4)));

// Barrier draining only LDS (lgkmcnt), NOT vmcnt: prefetched global loads for
// future chunks stay in flight across the per-chunk exchange barrier.
__device__ __forceinline__ void barrier_lds() {
  __asm__ volatile("s_waitcnt lgkmcnt(0)\n\ts_barrier" ::: "memory");
}

__device__ __forceinline__ v4f vmax4(v4f a, v4f b) {
  v4f r;
  r.x = fmaxf(a.x, b.x); r.y = fmaxf(a.y, b.y);
  r.z = fmaxf(a.z, b.z); r.w = fmaxf(a.w, b.w);
  return r;
}

// One 8-step chunk of this thread's 4 neurons: 32 VGPRs of SSA values.
struct Chunk { v4f x0, x1, x2, x3, x4, x5, x6, x7; };

// Plain vector loads -- visible to scheduler + waitcnt pass.
#define LOADC(buf, cc)                                                       \
  do {                                                                       \
    const float* _g = xg + (size_t)(cc) * (CHUNK_ * N_);                     \
    buf.x0 = *(const v4f*)(_g + 0 * N_);                                     \
    buf.x1 = *(const v4f*)(_g + 1 * N_);                                     \
    buf.x2 = *(const v4f*)(_g + 2 * N_);                                     \
    buf.x3 = *(const v4f*)(_g + 3 * N_);                                     \
    buf.x4 = *(const v4f*)(_g + 4 * N_);                                     \
    buf.x5 = *(const v4f*)(_g + 5 * N_);                                     \
    buf.x6 = *(const v4f*)(_g + 6 * N_);                                     \
    buf.x7 = *(const v4f*)(_g + 7 * N_);                                     \
  } while (0)

#define SPEC_STEP(xf)                                                        \
  do {                                                                       \
    cmax = vmax4(cmax, st);                                                  \
    v4f _t = (xf) + rr;                                                      \
    st = st * 0.9f + 0.1f * _t;                                              \
    rr = brec;                                                               \
  } while (0)

// Process one chunk: speculative no-spike pass over named fields (constant
// indices only); block-wide ballot; exact replay (rare) via `replay`.
#define PROCESS(buf, cc)                                                     \
  do {                                                                       \
    v4f st = state, rr = rec, cmax = state;                                  \
    SPEC_STEP(buf.x0); SPEC_STEP(buf.x1); SPEC_STEP(buf.x2);                 \
    SPEC_STEP(buf.x3); SPEC_STEP(buf.x4); SPEC_STEP(buf.x5);                 \
    SPEC_STEP(buf.x6); SPEC_STEP(buf.x7);                                    \
    float _m = fmaxf(fmaxf(cmax.x, cmax.y), fmaxf(cmax.z, cmax.w));          \
    int _any = (_m >= 1.0f);                                                 \
    const int _p = (cc) & 1;                                                 \
    unsigned long long _wm = __ballot(_any);                                 \
    if (lane == 0) s_cmask[_p][wv] = _wm;                                    \
    barrier_lds();                                                           \
    unsigned long long _ab =                                                 \
        s_cmask[_p][0] | s_cmask[_p][1] | s_cmask[_p][2] | s_cmask[_p][3];   \
    if (_ab == 0ULL) { state = st; rec = brec; }                             \
    else { replay(cc); }                                                     \
  } while (0)

__global__ __launch_bounds__(THREADS_, 1)
void lif_fused(const float* __restrict__ x, const float* __restrict__ w,
               const float* __restrict__ brec_g, float* __restrict__ out,
               unsigned long long* __restrict__ ws_rec,
               unsigned int* __restrict__ ws_cnt, int cap)
{
  // ---------------- zero path: blocks >= 32 clear the output ----------------
  if (blockIdx.x >= B_) {
    const size_t n4 = (size_t)B_ * T_ * N_ / 4;
    size_t i = (size_t)(blockIdx.x - B_) * THREADS_ + threadIdx.x;
    const size_t stride = (size_t)(gridDim.x - B_) * THREADS_;
    v4f* o4 = (v4f*)out;
    v4f z = (v4f)(0.f);
    for (; i < n4; i += stride) __builtin_nontemporal_store(z, &o4[i]);
    return;
  }

  // ---------------- lif path: blocks 0..31, one batch row each --------------
  const int b    = blockIdx.x;
  const int tid  = threadIdx.x;
  const int lane = tid & 63;
  const int wv   = tid >> 6;
  const int n0   = tid << 2;

  // Parity-double-buffered exchange: one barrier per chunk/step, no resets.
  __shared__ unsigned long long s_cmask[2][WAVES_];
  __shared__ unsigned long long s_mask [2][WAVES_];
  __shared__ v4f                s_val  [2][THREADS_];
  __shared__ unsigned int       s_spkcnt;

  if (tid == 0) s_spkcnt = 0;   // ordered by the first chunk's barrier_lds

  // this thread's 4-neuron column of batch row b
  const float* xg = x + (size_t)b * T_ * N_ + n0;

  v4f state = (v4f)(0.f);
  v4f rec   = (v4f)(0.f);                 // initial carry rec = 0 (NOT b_rec)
  const v4f brec = *(const v4f*)(brec_g + n0);

  // Exact replay of chunk cc (rare): re-reads x from GLOBAL (no register
  // arrays), per-step spike exchange, sparse rank-1 rec update, spike records.
  auto replay = [&](int cc) {
    v4f st = state;
    v4f r  = rec;
    const float* xrep = xg + (size_t)cc * (CHUNK_ * N_);
#pragma unroll 1
    for (int k = 0; k < CHUNK_; ++k) {
      const int q = k & 1;
      v4f xv = *(const v4f*)(xrep + (size_t)k * N_);
      float tx = xv.x + r.x, ty = xv.y + r.y, tz = xv.z + r.z, tw = xv.w + r.w;
      float ax = (st.x > 0.f) ? floorf(st.x) : 0.f;
      float ay = (st.y > 0.f) ? floorf(st.y) : 0.f;
      float az = (st.z > 0.f) ? floorf(st.z) : 0.f;
      float aw = (st.w > 0.f) ? floorf(st.w) : 0.f;
      int ms = (ax != 0.f) | (ay != 0.f) | (az != 0.f) | (aw != 0.f);
      if (ms) {
        v4f v; v.x = ax; v.y = ay; v.z = az; v.w = aw;
        s_val[q][tid] = v;
        unsigned int off = (unsigned int)((cc * CHUNK_ + k) * N_ + n0);
        float av[4] = {ax, ay, az, aw};
#pragma unroll
        for (int e = 0; e < 4; ++e) {
          if (av[e] != 0.f) {
            unsigned int idx = atomicAdd(&s_spkcnt, 1u);
            if ((int)idx < cap)
              ws_rec[(size_t)b * cap + idx] =
                  ((unsigned long long)(off + e) << 32) |
                  (unsigned long long)__float_as_uint(av[e]);
          }
        }
      }
      unsigned long long sm = __ballot(ms);
      if (lane == 0) s_mask[q][wv] = sm;
      st.x = (st.x - ax) * 0.9f + 0.1f * tx;
      st.y = (st.y - ay) * 0.9f + 0.1f * ty;
      st.z = (st.z - az) * 0.9f + 0.1f * tz;
      st.w = (st.w - aw) * 0.9f + 0.1f * tw;
      barrier_lds();
      // sparse rank-1 rec update: rec[n] = b_rec[n] + sum_j act[j]*w[n][j]
      v4f racc = brec;
#pragma unroll 1
      for (int w2 = 0; w2 < WAVES_; ++w2) {
        unsigned long long mm = s_mask[q][w2];
        while (mm) {
          int l = __builtin_ctzll(mm);
          mm &= mm - 1;
          int j = (w2 << 6) + l;
          v4f v = s_val[q][j];
          int jn = j << 2;
          if (v.x != 0.f) {
            racc.x += v.x * w[(size_t)(n0 + 0) * N_ + jn];
            racc.y += v.x * w[(size_t)(n0 + 1) * N_ + jn];
            racc.z += v.x * w[(size_t)(n0 + 2) * N_ + jn];
            racc.w += v.x * w[(size_t)(n0 + 3) * N_ + jn];
          }
          if (v.y != 0.f) {
            int j1 = jn + 1;
            racc.x += v.y * w[(size_t)(n0 + 0) * N_ + j1];
            racc.y += v.y * w[(size_t)(n0 + 1) * N_ + j1];
            racc.z += v.y * w[(size_t)(n0 + 2) * N_ + j1];
            racc.w += v.y * w[(size_t)(n0 + 3) * N_ + j1];
          }
          if (v.z != 0.f) {
            int j2 = jn + 2;
            racc.x += v.z * w[(size_t)(n0 + 0) * N_ + j2];
            racc.y += v.z * w[(size_t)(n0 + 1) * N_ + j2];
            racc.z += v.z * w[(size_t)(n0 + 2) * N_ + j2];
            racc.w += v.z * w[(size_t)(n0 + 3) * N_ + j2];
          }
          if (v.w != 0.f) {
            int j3 = jn + 3;
            racc.x += v.w * w[(size_t)(n0 + 0) * N_ + j3];
            racc.y += v.w * w[(size_t)(n0 + 1) * N_ + j3];
            racc.z += v.w * w[(size_t)(n0 + 2) * N_ + j3];
            racc.w += v.w * w[(size_t)(n0 + 3) * N_ + j3];
          }
        }
      }
      r = racc;
    }
    state = st;
    rec   = r;
  };

  // ---- depth-2 modulo-scheduled chunk pipeline over 3 register buffers ----
  // Steady state: chunks {c, c+1, c+2} in flight as SSA values; waitcnt pass
  // emits precise vmcnt before each buffer's first use.
  Chunk bufA, bufB, bufC;
  LOADC(bufA, 0);
  LOADC(bufB, 1);

  int c = 0;
#pragma unroll 1
  for (int t3 = 0; t3 < 41; ++t3) {   // processes chunks 0..122
    LOADC(bufC, c + 2);
    PROCESS(bufA, c);
    LOADC(bufA, c + 3);
    PROCESS(bufB, c + 1);
    LOADC(bufB, c + 4);
    PROCESS(bufC, c + 2);
    c += 3;
  }
  // tail: chunks 123 (bufA) and 124 (bufB) already loaded
  PROCESS(bufA, 123);
  PROCESS(bufB, 124);

  __syncthreads();                     // all replay appends done
  if (tid == 0) ws_cnt[b] = s_spkcnt;  // written unconditionally (ws poisoned)
}

// Apply the (few hundred) recorded spikes onto the zeroed output.
__global__ void scatter_spikes(const unsigned long long* __restrict__ rec,
                               const unsigned int* __restrict__ cnt,
                               float* __restrict__ out, int cap)
{
  int b = blockIdx.x;
  unsigned int n = cnt[b];
  if ((int)n > cap) n = cap;
  for (unsigned int i = threadIdx.x; i < n; i += blockDim.x) {
    unsigned long long r = rec[(size_t)b * cap + i];
    unsigned int off = (unsigned int)(r >> 32);
    float v = __uint_as_float((unsigned int)r);
    out[(size_t)b * (T_ * N_) + off] = v;
  }
}

extern "C" void kernel_launch(void* const* d_in, const int* in_sizes, int n_in,
                              void* d_out, int out_size, void* d_ws, size_t ws_size,
                              hipStream_t stream) {
  const float* x  = (const float*)d_in[0]; // [B,T,N] input_current
  const float* w  = (const float*)d_in[1]; // [N,N] w_rec (row-major [out,in])
  const float* br = (const float*)d_in[2]; // [N] b_rec
  float* out = (float*)d_out;              // [B,T,N] spikes

  // spike-record workspace layout: [32][cap] u64 records, then [32] u32 counts
  int cap = 4096;
  size_t need = (size_t)B_ * cap * 8 + B_ * 4;
  if (ws_size < need && ws_size > 256)
    cap = (int)((ws_size - 256) / ((size_t)B_ * 8));
  unsigned long long* rec = (unsigned long long*)d_ws;
  unsigned int* cnt = (unsigned int*)((char*)d_ws + (size_t)B_ * cap * 8);

  // blocks 0..31: sequential LIF scan (1 block/batch row);
  // blocks 32..: zero the output concurrently on the remaining CUs.
  lif_fused<<<B_ + ZBLOCKS_, THREADS_, 0, stream>>>(x, w, br, out, rec, cnt, cap);
  scatter_spikes<<<B_, THREADS_, 0, stream>>>(rec, cnt, out, cap);
}

// Round 7
// 330.888 us; speedup vs baseline: 1.0822x; 1.0409x over previous
//
#include <hip/hip_runtime.h>
#include <cstdint>
#include <cstddef>

// LIF recurrent SNN, sinabs ThresholdSubtract.
//   B=32 independent batch rows -> 1 block per batch, state in registers.
//   Spikes ~4.4 sigma -> speculate "no spike in chunk", exact replay on hit.
// Round-7: R6 + __builtin_amdgcn_sched_barrier(0) pins after each LOADC.
//   ROOT CAUSE (R1..R6 ledger): x is noalias+readonly, so its loads may
//   legally cross even "memory"-clobber asm barriers; the pre-RA scheduler's
//   RP-minimizing heuristic sinks every load to its single use -> 8 serialized
//   ~450cy L3 hits per chunk (3600cy/chunk, VGPR_Count 72 = no buffer live).
//   Prior failures were the same effect via different mechanisms:
//     R1 arrays/dynamic idx -> scratch; R2/R5 asm loads -> RA-opaque defs;
//     R4 LDS-DMA -> waitcnt pass can't disambiguate buffers -> vmcnt(0).
//   sched_barrier(0) survives to MIR as a side-effecting pseudo: machine
//   scheduler and MachineSink cannot move the loads across it -> loads for
//   chunk c+2 issue before chunk c's compute; waitcnt pass (per-register,
//   precise for plain loads) emits vmcnt(16)-class waits at first use.
#define B_       32
#define T_       1000
#define N_       1024
#define THREADS_ 256           // 4 waves; each thread owns 4 consecutive neurons
#define WAVES_   4
#define CHUNK_   8
#define ZBLOCKS_ 2048

typedef float v4f __attribute__((ext_vector_type(4)));

// Barrier draining only LDS (lgkmcnt), NOT vmcnt: prefetched global loads for
// future chunks stay in flight across the per-chunk exchange barrier.
__device__ __forceinline__ void barrier_lds() {
  __asm__ volatile("s_waitcnt lgkmcnt(0)\n\ts_barrier" ::: "memory");
}

__device__ __forceinline__ v4f vmax4(v4f a, v4f b) {
  v4f r;
  r.x = fmaxf(a.x, b.x); r.y = fmaxf(a.y, b.y);
  r.z = fmaxf(a.z, b.z); r.w = fmaxf(a.w, b.w);
  return r;
}

// One 8-step chunk of this thread's 4 neurons: 32 VGPRs of SSA values.
struct Chunk { v4f x0, x1, x2, x3, x4, x5, x6, x7; };

// Plain vector loads + a scheduling fence that pins them at the issue point.
#define LOADC(buf, cc)                                                       \
  do {                                                                       \
    const float* _g = xg + (size_t)(cc) * (CHUNK_ * N_);                     \
    buf.x0 = *(const v4f*)(_g + 0 * N_);                                     \
    buf.x1 = *(const v4f*)(_g + 1 * N_);                                     \
    buf.x2 = *(const v4f*)(_g + 2 * N_);                                     \
    buf.x3 = *(const v4f*)(_g + 3 * N_);                                     \
    buf.x4 = *(const v4f*)(_g + 4 * N_);                                     \
    buf.x5 = *(const v4f*)(_g + 5 * N_);                                     \
    buf.x6 = *(const v4f*)(_g + 6 * N_);                                     \
    buf.x7 = *(const v4f*)(_g + 7 * N_);                                     \
    __builtin_amdgcn_sched_barrier(0);  /* loads may not sink below */       \
  } while (0)

#define SPEC_STEP(xf)                                                        \
  do {                                                                       \
    cmax = vmax4(cmax, st);                                                  \
    v4f _t = (xf) + rr;                                                      \
    st = st * 0.9f + 0.1f * _t;                                              \
    rr = brec;                                                               \
  } while (0)

// Process one chunk: speculative no-spike pass over named fields (constant
// indices only); block-wide ballot; exact replay (rare) via `replay`.
#define PROCESS(buf, cc)                                                     \
  do {                                                                       \
    v4f st = state, rr = rec, cmax = state;                                  \
    SPEC_STEP(buf.x0); SPEC_STEP(buf.x1); SPEC_STEP(buf.x2);                 \
    SPEC_STEP(buf.x3); SPEC_STEP(buf.x4); SPEC_STEP(buf.x5);                 \
    SPEC_STEP(buf.x6); SPEC_STEP(buf.x7);                                    \
    float _m = fmaxf(fmaxf(cmax.x, cmax.y), fmaxf(cmax.z, cmax.w));          \
    int _any = (_m >= 1.0f);                                                 \
    const int _p = (cc) & 1;                                                 \
    unsigned long long _wm = __ballot(_any);                                 \
    if (lane == 0) s_cmask[_p][wv] = _wm;                                    \
    barrier_lds();                                                           \
    unsigned long long _ab =                                                 \
        s_cmask[_p][0] | s_cmask[_p][1] | s_cmask[_p][2] | s_cmask[_p][3];   \
    if (_ab == 0ULL) { state = st; rec = brec; }                             \
    else { replay(cc); }                                                     \
  } while (0)

__global__ __launch_bounds__(THREADS_, 1)
void lif_fused(const float* __restrict__ x, const float* __restrict__ w,
               const float* __restrict__ brec_g, float* __restrict__ out,
               unsigned long long* __restrict__ ws_rec,
               unsigned int* __restrict__ ws_cnt, int cap)
{
  // ---------------- zero path: blocks >= 32 clear the output ----------------
  if (blockIdx.x >= B_) {
    const size_t n4 = (size_t)B_ * T_ * N_ / 4;
    size_t i = (size_t)(blockIdx.x - B_) * THREADS_ + threadIdx.x;
    const size_t stride = (size_t)(gridDim.x - B_) * THREADS_;
    v4f* o4 = (v4f*)out;
    v4f z = (v4f)(0.f);
    for (; i < n4; i += stride) __builtin_nontemporal_store(z, &o4[i]);
    return;
  }

  // ---------------- lif path: blocks 0..31, one batch row each --------------
  const int b    = blockIdx.x;
  const int tid  = threadIdx.x;
  const int lane = tid & 63;
  const int wv   = tid >> 6;
  const int n0   = tid << 2;

  // Parity-double-buffered exchange: one barrier per chunk/step, no resets.
  __shared__ unsigned long long s_cmask[2][WAVES_];
  __shared__ unsigned long long s_mask [2][WAVES_];
  __shared__ v4f                s_val  [2][THREADS_];
  __shared__ unsigned int       s_spkcnt;

  if (tid == 0) s_spkcnt = 0;   // ordered by the first chunk's barrier_lds

  // this thread's 4-neuron column of batch row b
  const float* xg = x + (size_t)b * T_ * N_ + n0;

  v4f state = (v4f)(0.f);
  v4f rec   = (v4f)(0.f);                 // initial carry rec = 0 (NOT b_rec)
  const v4f brec = *(const v4f*)(brec_g + n0);

  // Exact replay of chunk cc (rare): re-reads x from GLOBAL (no register
  // arrays), per-step spike exchange, sparse rank-1 rec update, spike records.
  auto replay = [&](int cc) {
    v4f st = state;
    v4f r  = rec;
    const float* xrep = xg + (size_t)cc * (CHUNK_ * N_);
#pragma unroll 1
    for (int k = 0; k < CHUNK_; ++k) {
      const int q = k & 1;
      v4f xv = *(const v4f*)(xrep + (size_t)k * N_);
      float tx = xv.x + r.x, ty = xv.y + r.y, tz = xv.z + r.z, tw = xv.w + r.w;
      float ax = (st.x > 0.f) ? floorf(st.x) : 0.f;
      float ay = (st.y > 0.f) ? floorf(st.y) : 0.f;
      float az = (st.z > 0.f) ? floorf(st.z) : 0.f;
      float aw = (st.w > 0.f) ? floorf(st.w) : 0.f;
      int ms = (ax != 0.f) | (ay != 0.f) | (az != 0.f) | (aw != 0.f);
      if (ms) {
        v4f v; v.x = ax; v.y = ay; v.z = az; v.w = aw;
        s_val[q][tid] = v;
        unsigned int off = (unsigned int)((cc * CHUNK_ + k) * N_ + n0);
        float av[4] = {ax, ay, az, aw};
#pragma unroll
        for (int e = 0; e < 4; ++e) {
          if (av[e] != 0.f) {
            unsigned int idx = atomicAdd(&s_spkcnt, 1u);
            if ((int)idx < cap)
              ws_rec[(size_t)b * cap + idx] =
                  ((unsigned long long)(off + e) << 32) |
                  (unsigned long long)__float_as_uint(av[e]);
          }
        }
      }
      unsigned long long sm = __ballot(ms);
      if (lane == 0) s_mask[q][wv] = sm;
      st.x = (st.x - ax) * 0.9f + 0.1f * tx;
      st.y = (st.y - ay) * 0.9f + 0.1f * ty;
      st.z = (st.z - az) * 0.9f + 0.1f * tz;
      st.w = (st.w - aw) * 0.9f + 0.1f * tw;
      barrier_lds();
      // sparse rank-1 rec update: rec[n] = b_rec[n] + sum_j act[j]*w[n][j]
      v4f racc = brec;
#pragma unroll 1
      for (int w2 = 0; w2 < WAVES_; ++w2) {
        unsigned long long mm = s_mask[q][w2];
        while (mm) {
          int l = __builtin_ctzll(mm);
          mm &= mm - 1;
          int j = (w2 << 6) + l;
          v4f v = s_val[q][j];
          int jn = j << 2;
          if (v.x != 0.f) {
            racc.x += v.x * w[(size_t)(n0 + 0) * N_ + jn];
            racc.y += v.x * w[(size_t)(n0 + 1) * N_ + jn];
            racc.z += v.x * w[(size_t)(n0 + 2) * N_ + jn];
            racc.w += v.x * w[(size_t)(n0 + 3) * N_ + jn];
          }
          if (v.y != 0.f) {
            int j1 = jn + 1;
            racc.x += v.y * w[(size_t)(n0 + 0) * N_ + j1];
            racc.y += v.y * w[(size_t)(n0 + 1) * N_ + j1];
            racc.z += v.y * w[(size_t)(n0 + 2) * N_ + j1];
            racc.w += v.y * w[(size_t)(n0 + 3) * N_ + j1];
          }
          if (v.z != 0.f) {
            int j2 = jn + 2;
            racc.x += v.z * w[(size_t)(n0 + 0) * N_ + j2];
            racc.y += v.z * w[(size_t)(n0 + 1) * N_ + j2];
            racc.z += v.z * w[(size_t)(n0 + 2) * N_ + j2];
            racc.w += v.z * w[(size_t)(n0 + 3) * N_ + j2];
          }
          if (v.w != 0.f) {
            int j3 = jn + 3;
            racc.x += v.w * w[(size_t)(n0 + 0) * N_ + j3];
            racc.y += v.w * w[(size_t)(n0 + 1) * N_ + j3];
            racc.z += v.w * w[(size_t)(n0 + 2) * N_ + j3];
            racc.w += v.w * w[(size_t)(n0 + 3) * N_ + j3];
          }
        }
      }
      r = racc;
    }
    state = st;
    rec   = r;
  };

  // ---- depth-2 modulo-scheduled chunk pipeline over 3 register buffers ----
  // Steady state: chunks {c, c+1, c+2} in flight (16-24 loads); sched_barrier
  // pins issue order; waitcnt pass emits precise vmcnt at first use.
  Chunk bufA, bufB, bufC;
  LOADC(bufA, 0);
  LOADC(bufB, 1);

  int c = 0;
#pragma unroll 1
  for (int t3 = 0; t3 < 41; ++t3) {   // processes chunks 0..122
    LOADC(bufC, c + 2);
    PROCESS(bufA, c);
    LOADC(bufA, c + 3);
    PROCESS(bufB, c + 1);
    LOADC(bufB, c + 4);
    PROCESS(bufC, c + 2);
    c += 3;
  }
  // tail: chunks 123 (bufA) and 124 (bufB) already loaded
  PROCESS(bufA, 123);
  PROCESS(bufB, 124);

  __syncthreads();                     // all replay appends done
  if (tid == 0) ws_cnt[b] = s_spkcnt;  // written unconditionally (ws poisoned)
}

// Apply the (few hundred) recorded spikes onto the zeroed output.
__global__ void scatter_spikes(const unsigned long long* __restrict__ rec,
                               const unsigned int* __restrict__ cnt,
                               float* __restrict__ out, int cap)
{
  int b = blockIdx.x;
  unsigned int n = cnt[b];
  if ((int)n > cap) n = cap;
  for (unsigned int i = threadIdx.x; i < n; i += blockDim.x) {
    unsigned long long r = rec[(size_t)b * cap + i];
    unsigned int off = (unsigned int)(r >> 32);
    float v = __uint_as_float((unsigned int)r);
    out[(size_t)b * (T_ * N_) + off] = v;
  }
}

extern "C" void kernel_launch(void* const* d_in, const int* in_sizes, int n_in,
                              void* d_out, int out_size, void* d_ws, size_t ws_size,
                              hipStream_t stream) {
  const float* x  = (const float*)d_in[0]; // [B,T,N] input_current
  const float* w  = (const float*)d_in[1]; // [N,N] w_rec (row-major [out,in])
  const float* br = (const float*)d_in[2]; // [N] b_rec
  float* out = (float*)d_out;              // [B,T,N] spikes

  // spike-record workspace layout: [32][cap] u64 records, then [32] u32 counts
  int cap = 4096;
  size_t need = (size_t)B_ * cap * 8 + B_ * 4;
  if (ws_size < need && ws_size > 256)
    cap = (int)((ws_size - 256) / ((size_t)B_ * 8));
  unsigned long long* rec = (unsigned long long*)d_ws;
  unsigned int* cnt = (unsigned int*)((char*)d_ws + (size_t)B_ * cap * 8);

  // blocks 0..31: sequential LIF scan (1 block/batch row);
  // blocks 32..: zero the output concurrently on the remaining CUs.
  lif_fused<<<B_ + ZBLOCKS_, THREADS_, 0, stream>>>(x, w, br, out, rec, cnt, cap);
  scatter_spikes<<<B_, THREADS_, 0, stream>>>(rec, cnt, out, cap);
}